// Round 1
// baseline (2868.358 us; speedup 1.0000x reference)
//
#include <hip/hip_runtime.h>
#include <cstddef>

#define NN 16384   // nodes
#define FF 64      // F_IN == F_OUT
#define BM 64      // rows per block
#define BK 32      // k-chunk
#define LSP 68     // padded LDS stride for transposed L tile (16B-aligned: 68*4=272=16*17)

// ---------------------------------------------------------------------------
// T_out = alpha * (L @ T_in) + beta * T_sub        (N x N) @ (N x 64)
// grid = NN/BM = 256 blocks, 256 threads (4 waves). Micro-tile 2 rows x 8 cols.
// ---------------------------------------------------------------------------
__global__ __launch_bounds__(256) void cheb_gemm(
    const float* __restrict__ L, const float* __restrict__ Tin,
    const float* __restrict__ Tsub, float* __restrict__ Tout,
    float alpha, float beta)
{
    __shared__ float Ls[BK][LSP];  // transposed: Ls[k][m]
    __shared__ float Ts[BK][FF];   // Ts[k][n]

    const int tid = threadIdx.x;
    const int blockRow = blockIdx.x * BM;

    const int tx = tid & 7;        // col group
    const int ty = tid >> 3;       // row group (0..31)
    const int col0 = tx * 8;
    const int row0 = ty * 2;

    float acc[2][8];
#pragma unroll
    for (int r = 0; r < 2; ++r)
#pragma unroll
        for (int c = 0; c < 8; ++c) acc[r][c] = 0.f;

    // L tile: 64 rows x 32 k = 512 float4 -> thread handles f4 idx tid, tid+256
    const int lr0 = tid >> 3;            // 0..31  (second f4 -> row lr0+32)
    const int lk0 = (tid & 7) * 4;       // 0,4,...,28
    // T tile: 32 k-rows x 64 cols = 512 float4 -> idx tid, tid+256
    const int tr0 = tid >> 4;            // 0..15  (second f4 -> k-row tr0+16)
    const int tn0 = (tid & 15) * 4;

    const float* Lb0 = L + (size_t)(blockRow + lr0) * NN + lk0;
    const float* Lb1 = L + (size_t)(blockRow + lr0 + 32) * NN + lk0;

    float4 la, lb, ta, tb;

    // ---- prologue: load chunk 0 straight to LDS
    la = *(const float4*)(Lb0 + 0);
    lb = *(const float4*)(Lb1 + 0);
    ta = *(const float4*)(Tin + (size_t)(0 + tr0) * FF + tn0);
    tb = *(const float4*)(Tin + (size_t)(0 + tr0 + 16) * FF + tn0);
    {
        Ls[lk0 + 0][lr0] = la.x; Ls[lk0 + 1][lr0] = la.y;
        Ls[lk0 + 2][lr0] = la.z; Ls[lk0 + 3][lr0] = la.w;
        Ls[lk0 + 0][lr0 + 32] = lb.x; Ls[lk0 + 1][lr0 + 32] = lb.y;
        Ls[lk0 + 2][lr0 + 32] = lb.z; Ls[lk0 + 3][lr0 + 32] = lb.w;
        *(float4*)&Ts[tr0][tn0] = ta;
        *(float4*)&Ts[tr0 + 16][tn0] = tb;
    }
    __syncthreads();

    const int NCHUNK = NN / BK;  // 512
    for (int c = 0; c < NCHUNK; ++c) {
        const bool more = (c + 1) < NCHUNK;
        if (more) {
            const int kc = (c + 1) * BK;
            la = *(const float4*)(Lb0 + kc);
            lb = *(const float4*)(Lb1 + kc);
            ta = *(const float4*)(Tin + (size_t)(kc + tr0) * FF + tn0);
            tb = *(const float4*)(Tin + (size_t)(kc + tr0 + 16) * FF + tn0);
        }
#pragma unroll
        for (int k = 0; k < BK; ++k) {
            const float2 lv = *(const float2*)&Ls[k][row0];
            const float4 t0 = *(const float4*)&Ts[k][col0];
            const float4 t1 = *(const float4*)&Ts[k][col0 + 4];
            acc[0][0] += lv.x * t0.x; acc[0][1] += lv.x * t0.y;
            acc[0][2] += lv.x * t0.z; acc[0][3] += lv.x * t0.w;
            acc[0][4] += lv.x * t1.x; acc[0][5] += lv.x * t1.y;
            acc[0][6] += lv.x * t1.z; acc[0][7] += lv.x * t1.w;
            acc[1][0] += lv.y * t0.x; acc[1][1] += lv.y * t0.y;
            acc[1][2] += lv.y * t0.z; acc[1][3] += lv.y * t0.w;
            acc[1][4] += lv.y * t1.x; acc[1][5] += lv.y * t1.y;
            acc[1][6] += lv.y * t1.z; acc[1][7] += lv.y * t1.w;
        }
        __syncthreads();
        if (more) {
            Ls[lk0 + 0][lr0] = la.x; Ls[lk0 + 1][lr0] = la.y;
            Ls[lk0 + 2][lr0] = la.z; Ls[lk0 + 3][lr0] = la.w;
            Ls[lk0 + 0][lr0 + 32] = lb.x; Ls[lk0 + 1][lr0 + 32] = lb.y;
            Ls[lk0 + 2][lr0 + 32] = lb.z; Ls[lk0 + 3][lr0 + 32] = lb.w;
            *(float4*)&Ts[tr0][tn0] = ta;
            *(float4*)&Ts[tr0 + 16][tn0] = tb;
            __syncthreads();
        }
    }

    // ---- epilogue: Tout = alpha*acc + beta*Tsub
#pragma unroll
    for (int r = 0; r < 2; ++r) {
        const size_t rowIdx = (size_t)(blockRow + row0 + r) * FF + col0;
        float o[8];
#pragma unroll
        for (int c = 0; c < 8; ++c) o[c] = alpha * acc[r][c];
        if (beta != 0.f) {
            const float4 s0 = *(const float4*)(Tsub + rowIdx);
            const float4 s1 = *(const float4*)(Tsub + rowIdx + 4);
            o[0] += beta * s0.x; o[1] += beta * s0.y; o[2] += beta * s0.z; o[3] += beta * s0.w;
            o[4] += beta * s1.x; o[5] += beta * s1.y; o[6] += beta * s1.z; o[7] += beta * s1.w;
        }
        float4 v0, v1;
        v0.x = o[0]; v0.y = o[1]; v0.z = o[2]; v0.w = o[3];
        v1.x = o[4]; v1.y = o[5]; v1.z = o[6]; v1.w = o[7];
        *(float4*)(Tout + rowIdx) = v0;
        *(float4*)(Tout + rowIdx + 4) = v1;
    }
}

// ---------------------------------------------------------------------------
// out[row][col] (+)= bias[col] (init) / out  +  T[row][:] @ Wk[:][col]
// one wave per row (lane = output col); 4 rows per block.
// ---------------------------------------------------------------------------
__global__ __launch_bounds__(256) void out_update(
    const float* __restrict__ T, const float* __restrict__ Wk,
    const float* __restrict__ bias, float* __restrict__ out, int init)
{
    const int row = blockIdx.x * 4 + (threadIdx.x >> 6);
    const int col = threadIdx.x & 63;
    const float* t = T + (size_t)row * FF;
    const size_t oi = (size_t)row * FF + col;

    float acc = init ? bias[col] : out[oi];
#pragma unroll
    for (int f = 0; f < FF; ++f)
        acc += t[f] * Wk[f * FF + col];
    out[oi] = acc;
}

extern "C" void kernel_launch(void* const* d_in, const int* in_sizes, int n_in,
                              void* d_out, int out_size, void* d_ws, size_t ws_size,
                              hipStream_t stream)
{
    const float* x    = (const float*)d_in[0];
    const float* L    = (const float*)d_in[1];
    const float* W    = (const float*)d_in[2];   // (4, 64, 64)
    const float* bias = (const float*)d_in[3];
    float* out = (float*)d_out;

    float* T1 = (float*)d_ws;                    // N x 64 fp32 = 4 MB
    float* T2 = T1 + (size_t)NN * FF;            // second 4 MB

    const dim3 gb(NN / BM), bb(256);             // GEMM: 256 blocks
    const dim3 go(NN / 4), bo(256);              // epilogue: wave-per-row

    // out = bias + x@W0
    out_update<<<go, bo, 0, stream>>>(x, W + 0 * FF * FF, bias, out, 1);
    // T1 = L @ x
    cheb_gemm<<<gb, bb, 0, stream>>>(L, x, x, T1, 1.f, 0.f);
    out_update<<<go, bo, 0, stream>>>(T1, W + 1 * FF * FF, bias, out, 0);
    // T2 = 2*(L @ T1) - x
    cheb_gemm<<<gb, bb, 0, stream>>>(L, T1, x, T2, 2.f, -1.f);
    out_update<<<go, bo, 0, stream>>>(T2, W + 2 * FF * FF, bias, out, 0);
    // T3 = 2*(L @ T2) - T1   (in-place over T1: element-wise read-before-write)
    cheb_gemm<<<gb, bb, 0, stream>>>(L, T2, T1, T1, 2.f, -1.f);
    out_update<<<go, bo, 0, stream>>>(T1, W + 3 * FF * FF, bias, out, 0);
}

// Round 2
// 1753.000 us; speedup vs baseline: 1.6363x; 1.6363x over previous
//
#include <hip/hip_runtime.h>
#include <cstddef>

#define NN 16384   // nodes
#define FF 64      // F_IN == F_OUT
#define BM 64      // rows per block
#define BK 32      // k-chunk
#define LSP 66     // L tile stride (transposed [k][m]); even for b64 align, 66%32=2 -> 2-way write conflict (free)
#define TSP 72     // T tile stride [k][n]; 288B rows, 16B-aligned, spreads b128 write banks

// ---------------------------------------------------------------------------
// T_out = alpha * (L @ T_in) + beta * T_sub        (N x N) @ (N x 64)
// 256 blocks x 512 threads. In-block split-K x2: group g = tid>>8 handles
// k in [g*NN/2, (g+1)*NN/2). Double-buffered LDS, 1 barrier per chunk.
// Micro-tile 2 rows x 8 cols per thread. Partials combined through LDS.
// ---------------------------------------------------------------------------
__global__ __launch_bounds__(512) void cheb_gemm(
    const float* __restrict__ L, const float* __restrict__ Tin,
    const float* __restrict__ Tsub, float* __restrict__ Tout,
    float alpha, float beta)
{
    __shared__ float Ls[2][2][BK][LSP];  // [group][buf][k][m]   33792 B
    __shared__ float Ts[2][2][BK][TSP];  // [group][buf][k][n]   36864 B

    const int tid = threadIdx.x;
    const int g   = tid >> 8;        // split-K group 0/1 (wave-uniform)
    const int t   = tid & 255;
    const int blockRow = blockIdx.x * BM;
    const int kBase = g * (NN / 2);

    const int tx = t & 7;            // col group
    const int ty = t >> 3;           // row group (0..31)
    const int col0 = tx * 8;
    const int row0 = ty * 2;

    float acc[2][8];
#pragma unroll
    for (int r = 0; r < 2; ++r)
#pragma unroll
        for (int c = 0; c < 8; ++c) acc[r][c] = 0.f;

    // L tile loaders: 64 rows x 32 k = 512 float4 per group
    const int lr0 = t >> 3;          // 0..31  (second f4 -> row lr0+32)
    const int lk0 = (t & 7) * 4;     // 0,4,...,28
    // T tile loaders: 32 k-rows x 64 cols = 512 float4 per group
    const int tr0 = t >> 4;          // 0..15  (second f4 -> k-row tr0+16)
    const int tn0 = (t & 15) * 4;

    const float* Lb0 = L + (size_t)(blockRow + lr0) * NN + kBase + lk0;
    const float* Lb1 = Lb0 + (size_t)32 * NN;
    const float* Tb  = Tin + ((size_t)kBase + tr0) * FF + tn0;

    float4 la, lb, ta, tb;

    // ---- prologue: chunk 0 -> buf 0
    la = *(const float4*)(Lb0);
    lb = *(const float4*)(Lb1);
    ta = *(const float4*)(Tb);
    tb = *(const float4*)(Tb + (size_t)16 * FF);
    {
        float (*ls)[LSP] = Ls[g][0];
        float (*tsw)[TSP] = Ts[g][0];
        ls[lk0 + 0][lr0] = la.x; ls[lk0 + 1][lr0] = la.y;
        ls[lk0 + 2][lr0] = la.z; ls[lk0 + 3][lr0] = la.w;
        ls[lk0 + 0][lr0 + 32] = lb.x; ls[lk0 + 1][lr0 + 32] = lb.y;
        ls[lk0 + 2][lr0 + 32] = lb.z; ls[lk0 + 3][lr0 + 32] = lb.w;
        *(float4*)&tsw[tr0][tn0] = ta;
        *(float4*)&tsw[tr0 + 16][tn0] = tb;
    }
    __syncthreads();

    const int NC = (NN / 2) / BK;    // 256 chunks per group
    for (int c = 0; c < NC; ++c) {
        const bool more = (c + 1) < NC;
        if (more) {
            const size_t kc = (size_t)(c + 1) * BK;
            la = *(const float4*)(Lb0 + kc);
            lb = *(const float4*)(Lb1 + kc);
            ta = *(const float4*)(Tb + kc * FF);
            tb = *(const float4*)(Tb + (kc + 16) * FF);
        }
        const int cur = c & 1;
        const float* __restrict__ lsb = &Ls[g][cur][0][0];
        const float* __restrict__ tsb = &Ts[g][cur][0][0];
#pragma unroll
        for (int k = 0; k < BK; ++k) {
            const float2 lv = *(const float2*)(lsb + k * LSP + row0);
            const float4 t0 = *(const float4*)(tsb + k * TSP + col0);
            const float4 t1 = *(const float4*)(tsb + k * TSP + col0 + 4);
            acc[0][0] += lv.x * t0.x; acc[0][1] += lv.x * t0.y;
            acc[0][2] += lv.x * t0.z; acc[0][3] += lv.x * t0.w;
            acc[0][4] += lv.x * t1.x; acc[0][5] += lv.x * t1.y;
            acc[0][6] += lv.x * t1.z; acc[0][7] += lv.x * t1.w;
            acc[1][0] += lv.y * t0.x; acc[1][1] += lv.y * t0.y;
            acc[1][2] += lv.y * t0.z; acc[1][3] += lv.y * t0.w;
            acc[1][4] += lv.y * t1.x; acc[1][5] += lv.y * t1.y;
            acc[1][6] += lv.y * t1.z; acc[1][7] += lv.y * t1.w;
        }
        if (more) {
            const int nxt = cur ^ 1;
            float (*ls)[LSP] = Ls[g][nxt];
            float (*tsw)[TSP] = Ts[g][nxt];
            ls[lk0 + 0][lr0] = la.x; ls[lk0 + 1][lr0] = la.y;
            ls[lk0 + 2][lr0] = la.z; ls[lk0 + 3][lr0] = la.w;
            ls[lk0 + 0][lr0 + 32] = lb.x; ls[lk0 + 1][lr0 + 32] = lb.y;
            ls[lk0 + 2][lr0 + 32] = lb.z; ls[lk0 + 3][lr0 + 32] = lb.w;
            *(float4*)&tsw[tr0][tn0] = ta;
            *(float4*)&tsw[tr0 + 16][tn0] = tb;
        }
        __syncthreads();
    }

    // ---- combine split-K partials through LDS, then write
    float* comb = &Ls[0][0][0][0];   // 4096 floats needed; Ls area = 8448 floats
    if (g == 1) {
#pragma unroll
        for (int r = 0; r < 2; ++r) {
            float4 v0, v1;
            v0.x = alpha * acc[r][0]; v0.y = alpha * acc[r][1];
            v0.z = alpha * acc[r][2]; v0.w = alpha * acc[r][3];
            v1.x = alpha * acc[r][4]; v1.y = alpha * acc[r][5];
            v1.z = alpha * acc[r][6]; v1.w = alpha * acc[r][7];
            *(float4*)&comb[(row0 + r) * FF + col0]     = v0;
            *(float4*)&comb[(row0 + r) * FF + col0 + 4] = v1;
        }
    }
    __syncthreads();
    if (g == 0) {
#pragma unroll
        for (int r = 0; r < 2; ++r) {
            const size_t rowIdx = (size_t)(blockRow + row0 + r) * FF + col0;
            const float4 p0 = *(const float4*)&comb[(row0 + r) * FF + col0];
            const float4 p1 = *(const float4*)&comb[(row0 + r) * FF + col0 + 4];
            float o[8];
            o[0] = alpha * acc[r][0] + p0.x; o[1] = alpha * acc[r][1] + p0.y;
            o[2] = alpha * acc[r][2] + p0.z; o[3] = alpha * acc[r][3] + p0.w;
            o[4] = alpha * acc[r][4] + p1.x; o[5] = alpha * acc[r][5] + p1.y;
            o[6] = alpha * acc[r][6] + p1.z; o[7] = alpha * acc[r][7] + p1.w;
            if (beta != 0.f) {
                const float4 s0 = *(const float4*)(Tsub + rowIdx);
                const float4 s1 = *(const float4*)(Tsub + rowIdx + 4);
                o[0] += beta * s0.x; o[1] += beta * s0.y; o[2] += beta * s0.z; o[3] += beta * s0.w;
                o[4] += beta * s1.x; o[5] += beta * s1.y; o[6] += beta * s1.z; o[7] += beta * s1.w;
            }
            float4 v0, v1;
            v0.x = o[0]; v0.y = o[1]; v0.z = o[2]; v0.w = o[3];
            v1.x = o[4]; v1.y = o[5]; v1.z = o[6]; v1.w = o[7];
            *(float4*)(Tout + rowIdx) = v0;
            *(float4*)(Tout + rowIdx + 4) = v1;
        }
    }
}

// ---------------------------------------------------------------------------
// out[row][col] (+)= bias[col] (init) / out  +  T[row][:] @ Wk[:][col]
// one wave per row (lane = output col); 4 rows per block.
// ---------------------------------------------------------------------------
__global__ __launch_bounds__(256) void out_update(
    const float* __restrict__ T, const float* __restrict__ Wk,
    const float* __restrict__ bias, float* __restrict__ out, int init)
{
    const int row = blockIdx.x * 4 + (threadIdx.x >> 6);
    const int col = threadIdx.x & 63;
    const float* t = T + (size_t)row * FF;
    const size_t oi = (size_t)row * FF + col;

    float acc = init ? bias[col] : out[oi];
#pragma unroll
    for (int f = 0; f < FF; ++f)
        acc += t[f] * Wk[f * FF + col];
    out[oi] = acc;
}

extern "C" void kernel_launch(void* const* d_in, const int* in_sizes, int n_in,
                              void* d_out, int out_size, void* d_ws, size_t ws_size,
                              hipStream_t stream)
{
    const float* x    = (const float*)d_in[0];
    const float* L    = (const float*)d_in[1];
    const float* W    = (const float*)d_in[2];   // (4, 64, 64)
    const float* bias = (const float*)d_in[3];
    float* out = (float*)d_out;

    float* T1 = (float*)d_ws;                    // N x 64 fp32 = 4 MB
    float* T2 = T1 + (size_t)NN * FF;            // second 4 MB

    const dim3 gb(NN / BM), bb(512);             // GEMM: 256 blocks x 512 thr
    const dim3 go(NN / 4), bo(256);              // epilogue: wave-per-row

    // out = bias + x@W0
    out_update<<<go, bo, 0, stream>>>(x, W + 0 * FF * FF, bias, out, 1);
    // T1 = L @ x
    cheb_gemm<<<gb, bb, 0, stream>>>(L, x, x, T1, 1.f, 0.f);
    out_update<<<go, bo, 0, stream>>>(T1, W + 1 * FF * FF, bias, out, 0);
    // T2 = 2*(L @ T1) - x
    cheb_gemm<<<gb, bb, 0, stream>>>(L, T1, x, T2, 2.f, -1.f);
    out_update<<<go, bo, 0, stream>>>(T2, W + 2 * FF * FF, bias, out, 0);
    // T3 = 2*(L @ T2) - T1   (in-place over T1: element-wise read-before-write)
    cheb_gemm<<<gb, bb, 0, stream>>>(L, T2, T1, T1, 2.f, -1.f);
    out_update<<<go, bo, 0, stream>>>(T1, W + 3 * FF * FF, bias, out, 0);
}

// Round 3
// 747.473 us; speedup vs baseline: 3.8374x; 2.3452x over previous
//
#include <hip/hip_runtime.h>
#include <cstddef>
#include <cstdint>

#define NN 16384
#define FF 64
#define BM 64
#define BK 64
#define SK 2
#define KHALF (NN / SK)     // 8192
#define NC (KHALF / BK)     // 128 chunks per block

typedef __attribute__((ext_vector_type(8))) short bf16x8;
typedef __attribute__((ext_vector_type(4))) float f32x4;
typedef unsigned short ushort_t;

#define GLOBAL_AS __attribute__((address_space(1)))
#define LDS_AS    __attribute__((address_space(3)))

// truncate-split: f = hi + lo (+ ~2^-16 rel dropped); hi/lo as bf16 bit patterns
__device__ __forceinline__ void f32_split(float f, ushort_t& h, ushort_t& l) {
    unsigned u = __builtin_bit_cast(unsigned, f);
    h = (ushort_t)(u >> 16);
    float hf = __builtin_bit_cast(float, u & 0xFFFF0000u);
    float lo = f - hf;                       // exact (Sterbenz)
    l = (ushort_t)(__builtin_bit_cast(unsigned, lo) >> 16);
}

// ---------------------------------------------------------------------------
// Transpose + hi/lo split:  T fp32 [N][64]  ->  Th, Tl bf16 [64][N]
// ---------------------------------------------------------------------------
__global__ __launch_bounds__(256) void convT(const float* __restrict__ T,
                                             ushort_t* __restrict__ Th,
                                             ushort_t* __restrict__ Tl)
{
    __shared__ float S[64][68];
    const int t = threadIdx.x;
    const int rb = blockIdx.x * 64;
    {
        const int row = t >> 2;
        const int c0 = (t & 3) * 16;
        const float* src = T + (size_t)(rb + row) * FF + c0;
        *(float4*)&S[row][c0 + 0]  = *(const float4*)(src + 0);
        *(float4*)&S[row][c0 + 4]  = *(const float4*)(src + 4);
        *(float4*)&S[row][c0 + 8]  = *(const float4*)(src + 8);
        *(float4*)&S[row][c0 + 12] = *(const float4*)(src + 12);
    }
    __syncthreads();
    const int cc = t >> 2;
    const int r0 = (t & 3) * 16;
    ushort_t hh[16], ll[16];
#pragma unroll
    for (int i = 0; i < 16; ++i)
        f32_split(S[r0 + i][cc], hh[i], ll[i]);
    unsigned wh[8], wl[8];
#pragma unroll
    for (int j = 0; j < 8; ++j) {
        wh[j] = (unsigned)hh[2 * j] | ((unsigned)hh[2 * j + 1] << 16);
        wl[j] = (unsigned)ll[2 * j] | ((unsigned)ll[2 * j + 1] << 16);
    }
    const size_t o = (size_t)cc * NN + rb + r0;
    *(uint4*)(Th + o)     = make_uint4(wh[0], wh[1], wh[2], wh[3]);
    *(uint4*)(Th + o + 8) = make_uint4(wh[4], wh[5], wh[6], wh[7]);
    *(uint4*)(Tl + o)     = make_uint4(wl[0], wl[1], wl[2], wl[3]);
    *(uint4*)(Tl + o + 8) = make_uint4(wl[4], wl[5], wl[6], wl[7]);
}

// ---------------------------------------------------------------------------
// P[s] = L[:, kslice] @ T[kslice, :]   via bf16 hi/lo-split MFMA.
// grid 512: s = bx>>8 (split-K), m = bx&255. 256 thr = 4 waves (2x2 of 32x32).
// A: fp32 global -> reg -> split -> swizzled LDS.  B: global_load_lds of
// pre-transposed Th/Tl with pre-swizzled per-lane source.
// ---------------------------------------------------------------------------
__global__ __launch_bounds__(256) void cheb_gemm_mfma(
    const float* __restrict__ L, const ushort_t* __restrict__ Th,
    const ushort_t* __restrict__ Tl, float* __restrict__ P)
{
    __shared__ ushort_t Ah[2][BM * BK];
    __shared__ ushort_t Al[2][BM * BK];
    __shared__ ushort_t Bh[2][FF * BK];
    __shared__ ushort_t Bl[2][FF * BK];

    const int tid  = threadIdx.x;
    const int lane = tid & 63;
    const int w    = tid >> 6;
    const int s    = blockIdx.x >> 8;
    const int m    = blockIdx.x & 255;
    const int row0g = m * BM;
    const int kbase = s * KHALF;

    const int wm = w >> 1, wn = w & 1;      // wave tile (32x32) coords
    const int frow = lane & 15;             // row (A) / col (B) within 16-tile
    const int fk8  = (lane >> 4) * 8;       // k-offset base

    // A staging: thread covers rows arow+16p, k = akq*4..+3
    const int arow = w * 4 + (lane >> 4);
    const int akq  = lane & 15;
    const int axor = (arow & 7) << 4;

    // B staging: wave picks hi/lo tile and 4 col-octets
    const ushort_t* Tsrc = (w & 1) ? Tl : Th;
    const int boct0 = (w >> 1) * 4;

    f32x4 acc[2][2];
#pragma unroll
    for (int i = 0; i < 2; ++i)
#pragma unroll
        for (int j = 0; j < 2; ++j) acc[i][j] = (f32x4)0.f;

    float4 va[4];

    const float* Labase = L + (size_t)(row0g + arow) * NN + kbase + akq * 4;

#define ISSUE_B(c, slot)                                                        \
    {                                                                           \
        const size_t kc = (size_t)(c) * BK;                                     \
        char* bbase = (char*)((w & 1) ? Bl[slot] : Bh[slot]);                   \
        _Pragma("unroll")                                                       \
        for (int o = 0; o < 4; ++o) {                                           \
            const int oct = boct0 + o;                                          \
            const int col = oct * 8 + (lane >> 3);                              \
            const ushort_t* g = Tsrc + (size_t)col * NN + kbase + kc            \
                                + (((lane & 7) ^ (col & 7)) * 8);               \
            __builtin_amdgcn_global_load_lds((const GLOBAL_AS void*)g,          \
                (LDS_AS void*)(bbase + oct * 1024), 16, 0, 0);                  \
        }                                                                       \
    }

#define LOAD_A(c)                                                               \
    {                                                                           \
        const float* g = Labase + (size_t)(c) * BK;                             \
        va[0] = *(const float4*)(g);                                            \
        va[1] = *(const float4*)(g + (size_t)16 * NN);                          \
        va[2] = *(const float4*)(g + (size_t)32 * NN);                          \
        va[3] = *(const float4*)(g + (size_t)48 * NN);                          \
    }

#define CONV_WRITE_A(slot)                                                      \
    {                                                                           \
        char* ahb = (char*)Ah[slot];                                            \
        char* alb = (char*)Al[slot];                                            \
        _Pragma("unroll")                                                       \
        for (int p = 0; p < 4; ++p) {                                           \
            const int r = arow + p * 16;                                        \
            ushort_t h0, h1, h2, h3, l0, l1, l2, l3;                            \
            f32_split(va[p].x, h0, l0);                                         \
            f32_split(va[p].y, h1, l1);                                         \
            f32_split(va[p].z, h2, l2);                                         \
            f32_split(va[p].w, h3, l3);                                         \
            const unsigned hi01 = (unsigned)h0 | ((unsigned)h1 << 16);          \
            const unsigned hi23 = (unsigned)h2 | ((unsigned)h3 << 16);          \
            const unsigned lo01 = (unsigned)l0 | ((unsigned)l1 << 16);          \
            const unsigned lo23 = (unsigned)l2 | ((unsigned)l3 << 16);          \
            const int byte = (r * 128 + akq * 8) ^ axor;                        \
            *(uint2*)(ahb + byte) = make_uint2(hi01, hi23);                     \
            *(uint2*)(alb + byte) = make_uint2(lo01, lo23);                     \
        }                                                                       \
    }

    // ---- prologue: chunk 0 -> slot 0
    ISSUE_B(0, 0)
    LOAD_A(0)
    CONV_WRITE_A(0)
    __syncthreads();

    for (int c = 0; c < NC; ++c) {
        const int slot = c & 1;
        if (c + 1 < NC) {
            ISSUE_B(c + 1, slot ^ 1)
            LOAD_A(c + 1)
        }
        // ---- compute chunk c
        {
            const char* ahb = (const char*)Ah[slot];
            const char* alb = (const char*)Al[slot];
            const char* bhb = (const char*)Bh[slot];
            const char* blb = (const char*)Bl[slot];
#pragma unroll
            for (int ks = 0; ks < 2; ++ks) {
                const int kk = ks * 32 + fk8;
                bf16x8 Afh[2], Afl[2], Bfh[2], Bfl[2];
#pragma unroll
                for (int mt = 0; mt < 2; ++mt) {
                    const int row = wm * 32 + mt * 16 + frow;
                    const int off = (row * 128 + kk * 2) ^ ((row & 7) << 4);
                    Afh[mt] = *(const bf16x8*)(ahb + off);
                    Afl[mt] = *(const bf16x8*)(alb + off);
                }
#pragma unroll
                for (int nt = 0; nt < 2; ++nt) {
                    const int col = wn * 32 + nt * 16 + frow;
                    const int off = (col * 128 + kk * 2) ^ ((col & 7) << 4);
                    Bfh[nt] = *(const bf16x8*)(bhb + off);
                    Bfl[nt] = *(const bf16x8*)(blb + off);
                }
#pragma unroll
                for (int mt = 0; mt < 2; ++mt)
#pragma unroll
                    for (int nt = 0; nt < 2; ++nt) {
                        acc[mt][nt] = __builtin_amdgcn_mfma_f32_16x16x32_bf16(
                            Afh[mt], Bfh[nt], acc[mt][nt], 0, 0, 0);
                        acc[mt][nt] = __builtin_amdgcn_mfma_f32_16x16x32_bf16(
                            Afh[mt], Bfl[nt], acc[mt][nt], 0, 0, 0);
                        acc[mt][nt] = __builtin_amdgcn_mfma_f32_16x16x32_bf16(
                            Afl[mt], Bfh[nt], acc[mt][nt], 0, 0, 0);
                    }
            }
        }
        if (c + 1 < NC) CONV_WRITE_A(slot ^ 1)
        __syncthreads();
    }

    // ---- write partial: C/D layout col=lane&15, row=(lane>>4)*4+r  (m89)
    float* Pp = P + (size_t)s * NN * FF;
#pragma unroll
    for (int mt = 0; mt < 2; ++mt)
#pragma unroll
        for (int nt = 0; nt < 2; ++nt) {
            const int row = row0g + wm * 32 + mt * 16 + (lane >> 4) * 4;
            const int col = wn * 32 + nt * 16 + frow;
#pragma unroll
            for (int r = 0; r < 4; ++r)
                Pp[(size_t)(row + r) * FF + col] = acc[mt][nt][r];
        }
#undef ISSUE_B
#undef LOAD_A
#undef CONV_WRITE_A
}

// ---------------------------------------------------------------------------
// Tout = alpha*(P0+P1) + beta*Tsub
// ---------------------------------------------------------------------------
__global__ __launch_bounds__(256) void reduce_axpby(
    const float* __restrict__ P0, const float* __restrict__ P1,
    const float* __restrict__ Tsub, float* __restrict__ Tout,
    float alpha, float beta)
{
    const int total = NN * FF / 4;
    for (int i = blockIdx.x * blockDim.x + threadIdx.x; i < total;
         i += gridDim.x * blockDim.x) {
        const float4 p0 = ((const float4*)P0)[i];
        const float4 p1 = ((const float4*)P1)[i];
        const float4 ts = ((const float4*)Tsub)[i];
        float4 o;
        o.x = alpha * (p0.x + p1.x) + beta * ts.x;
        o.y = alpha * (p0.y + p1.y) + beta * ts.y;
        o.z = alpha * (p0.z + p1.z) + beta * ts.z;
        o.w = alpha * (p0.w + p1.w) + beta * ts.w;
        ((float4*)Tout)[i] = o;
    }
}

// ---------------------------------------------------------------------------
// out[row][col] (+)= bias[col] (init) / out  +  T[row][:] @ Wk[:][col]
// ---------------------------------------------------------------------------
__global__ __launch_bounds__(256) void out_update(
    const float* __restrict__ T, const float* __restrict__ Wk,
    const float* __restrict__ bias, float* __restrict__ out, int init)
{
    const int row = blockIdx.x * 4 + (threadIdx.x >> 6);
    const int col = threadIdx.x & 63;
    const float* t = T + (size_t)row * FF;
    const size_t oi = (size_t)row * FF + col;

    float acc = init ? bias[col] : out[oi];
#pragma unroll
    for (int f = 0; f < FF; ++f)
        acc += t[f] * Wk[f * FF + col];
    out[oi] = acc;
}

extern "C" void kernel_launch(void* const* d_in, const int* in_sizes, int n_in,
                              void* d_out, int out_size, void* d_ws, size_t ws_size,
                              hipStream_t stream)
{
    const float* x    = (const float*)d_in[0];
    const float* L    = (const float*)d_in[1];
    const float* W    = (const float*)d_in[2];   // (4, 64, 64)
    const float* bias = (const float*)d_in[3];
    float* out = (float*)d_out;

    const size_t M1 = (size_t)NN * FF;           // 1M elems
    float* wsf = (float*)d_ws;
    float* T1 = wsf;
    float* T2 = wsf + M1;
    float* T3 = wsf + 2 * M1;
    float* P0 = wsf + 3 * M1;                    // P1 = P0 + M1 (gemm indexes by s)
    float* P1 = wsf + 4 * M1;
    ushort_t* Tht = (ushort_t*)(wsf + 5 * M1);
    ushort_t* Tlt = Tht + M1;

    const dim3 gg(256 * SK), bg(256);            // gemm
    const dim3 gc(NN / 64),  bc(256);            // convT
    const dim3 gr(512),      br(256);            // reduce
    const dim3 go(NN / 4),   bo(256);            // out_update

    out_update<<<go, bo, 0, stream>>>(x, W + 0 * FF * FF, bias, out, 1);

    // T1 = L @ x
    convT<<<gc, bc, 0, stream>>>(x, Tht, Tlt);
    cheb_gemm_mfma<<<gg, bg, 0, stream>>>(L, Tht, Tlt, P0);
    reduce_axpby<<<gr, br, 0, stream>>>(P0, P1, x, T1, 1.f, 0.f);
    out_update<<<go, bo, 0, stream>>>(T1, W + 1 * FF * FF, bias, out, 0);

    // T2 = 2*(L @ T1) - x
    convT<<<gc, bc, 0, stream>>>(T1, Tht, Tlt);
    cheb_gemm_mfma<<<gg, bg, 0, stream>>>(L, Tht, Tlt, P0);
    reduce_axpby<<<gr, br, 0, stream>>>(P0, P1, x, T2, 2.f, -1.f);
    out_update<<<go, bo, 0, stream>>>(T2, W + 2 * FF * FF, bias, out, 0);

    // T3 = 2*(L @ T2) - T1
    convT<<<gc, bc, 0, stream>>>(T2, Tht, Tlt);
    cheb_gemm_mfma<<<gg, bg, 0, stream>>>(L, Tht, Tlt, P0);
    reduce_axpby<<<gr, br, 0, stream>>>(P0, P1, T1, T3, 2.f, -1.f);
    out_update<<<go, bo, 0, stream>>>(T3, W + 3 * FF * FF, bias, out, 0);
}

// Round 4
// 735.931 us; speedup vs baseline: 3.8976x; 1.0157x over previous
//
#include <hip/hip_runtime.h>
#include <cstddef>
#include <cstdint>

#define NN 16384
#define FF 64
#define BM 64
#define BK 64
#define SK 4
#define KQ (NN / SK)        // 4096 k per split-K slice
#define NC (KQ / BK)        // 64 chunks per block

typedef __attribute__((ext_vector_type(8))) short bf16x8;
typedef __attribute__((ext_vector_type(4))) float f32x4;
typedef unsigned short ushort_t;

#define GLOBAL_AS __attribute__((address_space(1)))
#define LDS_AS    __attribute__((address_space(3)))

// truncate-split: f = hi + lo (+ ~2^-16 rel dropped); hi/lo as bf16 bit patterns
__device__ __forceinline__ void f32_split(float f, ushort_t& h, ushort_t& l) {
    unsigned u = __builtin_bit_cast(unsigned, f);
    h = (ushort_t)(u >> 16);
    float hf = __builtin_bit_cast(float, u & 0xFFFF0000u);
    float lo = f - hf;                       // exact (Sterbenz)
    l = (ushort_t)(__builtin_bit_cast(unsigned, lo) >> 16);
}

// ---------------------------------------------------------------------------
// Transpose + hi/lo split:  T fp32 [N][64]  ->  Th, Tl bf16 [64][N]
// (only used once, for x)
// ---------------------------------------------------------------------------
__global__ __launch_bounds__(256) void convT(const float* __restrict__ T,
                                             ushort_t* __restrict__ Th,
                                             ushort_t* __restrict__ Tl)
{
    __shared__ float S[64][68];
    const int t = threadIdx.x;
    const int rb = blockIdx.x * 64;
    {
        const int row = t >> 2;
        const int c0 = (t & 3) * 16;
        const float* src = T + (size_t)(rb + row) * FF + c0;
        *(float4*)&S[row][c0 + 0]  = *(const float4*)(src + 0);
        *(float4*)&S[row][c0 + 4]  = *(const float4*)(src + 4);
        *(float4*)&S[row][c0 + 8]  = *(const float4*)(src + 8);
        *(float4*)&S[row][c0 + 12] = *(const float4*)(src + 12);
    }
    __syncthreads();
    const int cc = t >> 2;
    const int r0 = (t & 3) * 16;
    ushort_t hh[16], ll[16];
#pragma unroll
    for (int i = 0; i < 16; ++i)
        f32_split(S[r0 + i][cc], hh[i], ll[i]);
    unsigned wh[8], wl[8];
#pragma unroll
    for (int j = 0; j < 8; ++j) {
        wh[j] = (unsigned)hh[2 * j] | ((unsigned)hh[2 * j + 1] << 16);
        wl[j] = (unsigned)ll[2 * j] | ((unsigned)ll[2 * j + 1] << 16);
    }
    const size_t o = (size_t)cc * NN + rb + r0;
    *(uint4*)(Th + o)     = make_uint4(wh[0], wh[1], wh[2], wh[3]);
    *(uint4*)(Th + o + 8) = make_uint4(wh[4], wh[5], wh[6], wh[7]);
    *(uint4*)(Tl + o)     = make_uint4(wl[0], wl[1], wl[2], wl[3]);
    *(uint4*)(Tl + o + 8) = make_uint4(wl[4], wl[5], wl[6], wl[7]);
}

// ---------------------------------------------------------------------------
// P[s] = L[:, kslice_s] @ T[kslice_s, :]   via bf16 hi/lo-split MFMA.
// grid SK*256: s = bx>>8, m = bx&255. 256 thr = 4 waves (2x2 of 32x32 tiles).
// ---------------------------------------------------------------------------
__global__ __launch_bounds__(256) void cheb_gemm_mfma(
    const float* __restrict__ L, const ushort_t* __restrict__ Th,
    const ushort_t* __restrict__ Tl, float* __restrict__ P)
{
    __shared__ ushort_t Ah[2][BM * BK];
    __shared__ ushort_t Al[2][BM * BK];
    __shared__ ushort_t Bh[2][FF * BK];
    __shared__ ushort_t Bl[2][FF * BK];

    const int tid  = threadIdx.x;
    const int lane = tid & 63;
    const int w    = tid >> 6;
    const int s    = blockIdx.x >> 8;
    const int m    = blockIdx.x & 255;
    const int row0g = m * BM;
    const int kbase = s * KQ;

    const int wm = w >> 1, wn = w & 1;      // wave tile (32x32) coords
    const int frow = lane & 15;             // row (A) / col (B) within 16-tile
    const int fk8  = (lane >> 4) * 8;       // k-offset base

    // A staging: thread covers rows arow+16p, k = akq*4..+3
    const int arow = w * 4 + (lane >> 4);
    const int akq  = lane & 15;
    const int axor = (arow & 7) << 4;

    // B staging: wave picks hi/lo tile and 4 col-octets
    const ushort_t* Tsrc = (w & 1) ? Tl : Th;
    const int boct0 = (w >> 1) * 4;

    f32x4 acc[2][2];
#pragma unroll
    for (int i = 0; i < 2; ++i)
#pragma unroll
        for (int j = 0; j < 2; ++j) acc[i][j] = (f32x4)0.f;

    float4 va[4];

    const float* Labase = L + (size_t)(row0g + arow) * NN + kbase + akq * 4;

#define ISSUE_B(c, slot)                                                        \
    {                                                                           \
        const size_t kc = (size_t)(c) * BK;                                     \
        char* bbase = (char*)((w & 1) ? Bl[slot] : Bh[slot]);                   \
        _Pragma("unroll")                                                       \
        for (int o = 0; o < 4; ++o) {                                           \
            const int oct = boct0 + o;                                          \
            const int col = oct * 8 + (lane >> 3);                              \
            const ushort_t* g = Tsrc + (size_t)col * NN + kbase + kc            \
                                + (((lane & 7) ^ (col & 7)) * 8);               \
            __builtin_amdgcn_global_load_lds((const GLOBAL_AS void*)g,          \
                (LDS_AS void*)(bbase + oct * 1024), 16, 0, 0);                  \
        }                                                                       \
    }

#define LOAD_A(c)                                                               \
    {                                                                           \
        const float* g = Labase + (size_t)(c) * BK;                             \
        va[0] = *(const float4*)(g);                                            \
        va[1] = *(const float4*)(g + (size_t)16 * NN);                          \
        va[2] = *(const float4*)(g + (size_t)32 * NN);                          \
        va[3] = *(const float4*)(g + (size_t)48 * NN);                          \
    }

#define CONV_WRITE_A(slot)                                                      \
    {                                                                           \
        char* ahb = (char*)Ah[slot];                                            \
        char* alb = (char*)Al[slot];                                            \
        _Pragma("unroll")                                                       \
        for (int p = 0; p < 4; ++p) {                                           \
            const int r = arow + p * 16;                                        \
            ushort_t h0, h1, h2, h3, l0, l1, l2, l3;                            \
            f32_split(va[p].x, h0, l0);                                         \
            f32_split(va[p].y, h1, l1);                                         \
            f32_split(va[p].z, h2, l2);                                         \
            f32_split(va[p].w, h3, l3);                                         \
            const unsigned hi01 = (unsigned)h0 | ((unsigned)h1 << 16);          \
            const unsigned hi23 = (unsigned)h2 | ((unsigned)h3 << 16);          \
            const unsigned lo01 = (unsigned)l0 | ((unsigned)l1 << 16);          \
            const unsigned lo23 = (unsigned)l2 | ((unsigned)l3 << 16);          \
            const int byte = (r * 128 + akq * 8) ^ axor;                        \
            *(uint2*)(ahb + byte) = make_uint2(hi01, hi23);                     \
            *(uint2*)(alb + byte) = make_uint2(lo01, lo23);                     \
        }                                                                       \
    }

    // ---- prologue: chunk 0 -> slot 0
    ISSUE_B(0, 0)
    LOAD_A(0)
    CONV_WRITE_A(0)
    __syncthreads();

    for (int c = 0; c < NC; ++c) {
        const int slot = c & 1;
        if (c + 1 < NC) {
            ISSUE_B(c + 1, slot ^ 1)
            LOAD_A(c + 1)
        }
        // ---- compute chunk c
        {
            const char* ahb = (const char*)Ah[slot];
            const char* alb = (const char*)Al[slot];
            const char* bhb = (const char*)Bh[slot];
            const char* blb = (const char*)Bl[slot];
#pragma unroll
            for (int ks = 0; ks < 2; ++ks) {
                const int kk = ks * 32 + fk8;
                bf16x8 Afh[2], Afl[2], Bfh[2], Bfl[2];
#pragma unroll
                for (int mt = 0; mt < 2; ++mt) {
                    const int row = wm * 32 + mt * 16 + frow;
                    const int off = (row * 128 + kk * 2) ^ ((row & 7) << 4);
                    Afh[mt] = *(const bf16x8*)(ahb + off);
                    Afl[mt] = *(const bf16x8*)(alb + off);
                }
#pragma unroll
                for (int nt = 0; nt < 2; ++nt) {
                    const int col = wn * 32 + nt * 16 + frow;
                    const int off = (col * 128 + kk * 2) ^ ((col & 7) << 4);
                    Bfh[nt] = *(const bf16x8*)(bhb + off);
                    Bfl[nt] = *(const bf16x8*)(blb + off);
                }
#pragma unroll
                for (int mt = 0; mt < 2; ++mt)
#pragma unroll
                    for (int nt = 0; nt < 2; ++nt) {
                        acc[mt][nt] = __builtin_amdgcn_mfma_f32_16x16x32_bf16(
                            Afh[mt], Bfh[nt], acc[mt][nt], 0, 0, 0);
                        acc[mt][nt] = __builtin_amdgcn_mfma_f32_16x16x32_bf16(
                            Afh[mt], Bfl[nt], acc[mt][nt], 0, 0, 0);
                        acc[mt][nt] = __builtin_amdgcn_mfma_f32_16x16x32_bf16(
                            Afl[mt], Bfh[nt], acc[mt][nt], 0, 0, 0);
                    }
            }
        }
        if (c + 1 < NC) CONV_WRITE_A(slot ^ 1)
        __syncthreads();
    }

    // ---- write partial: C/D layout col=lane&15, row=(lane>>4)*4+r  (m89)
    float* Pp = P + (size_t)s * NN * FF;
#pragma unroll
    for (int mt = 0; mt < 2; ++mt)
#pragma unroll
        for (int nt = 0; nt < 2; ++nt) {
            const int row = row0g + wm * 32 + mt * 16 + (lane >> 4) * 4;
            const int col = wn * 32 + nt * 16 + frow;
#pragma unroll
            for (int r = 0; r < 4; ++r)
                Pp[(size_t)(row + r) * FF + col] = acc[mt][nt][r];
        }
#undef ISSUE_B
#undef LOAD_A
#undef CONV_WRITE_A
}

// ---------------------------------------------------------------------------
// Fused per-hop epilogue. Block handles 64 rows (grid 256).
//   t = alpha*(P0+P1+P2+P3) + beta*Tsub           (phase A, -> LDS transposed)
//   [Tout]   = t                                  (optional fp32 store)
//   [Th/Tl]  = transpose+split(t)                 (optional, B for next GEMM)
//   out      = (Xin ? bias + Xin@W0 : out) + t@Wk (micro-tiled 2x8 per thread)
// ---------------------------------------------------------------------------
__global__ __launch_bounds__(256) void post_hop(
    const float* __restrict__ P,
    const float* __restrict__ Tsub,
    const float* __restrict__ Xin,
    const float* __restrict__ W0w,
    const float* __restrict__ Wkw,
    const float* __restrict__ bias,
    float* __restrict__ Tout,
    ushort_t* __restrict__ Th, ushort_t* __restrict__ Tl,
    float* __restrict__ out,
    float alpha, float beta)
{
    __shared__ float ST[64][68];    // ST[f][row] = t[rb+row][f]
    __shared__ float ST2[64][68];   // x transposed (post1 only)
    __shared__ float WK[64][64];
    __shared__ float WX[64][64];

    const int tid = threadIdx.x;
    const int rb = blockIdx.x * 64;
    const size_t M1 = (size_t)NN * FF;

    // ---- stage W into LDS (each thread: 4 float4)
    {
        float4* wd = (float4*)&WK[0][0];
        const float4* ws = (const float4*)Wkw;
#pragma unroll
        for (int j = 0; j < 4; ++j) wd[tid * 4 + j] = ws[tid * 4 + j];
        if (Xin) {
            float4* xd = (float4*)&WX[0][0];
            const float4* xs = (const float4*)W0w;
#pragma unroll
            for (int j = 0; j < 4; ++j) xd[tid * 4 + j] = xs[tid * 4 + j];
        }
    }

    // ---- phase A: t = alpha*sum(P) + beta*Tsub ; scatter into ST (transposed)
    {
        const int arow = tid >> 2;
        const int ac0 = (tid & 3) * 16;
        const size_t rowOff = (size_t)(rb + arow) * FF + ac0;
#pragma unroll
        for (int j = 0; j < 4; ++j) {
            const size_t o = rowOff + 4 * j;
            float4 s  = *(const float4*)(P + o);
            float4 p1 = *(const float4*)(P + M1 + o);
            float4 p2 = *(const float4*)(P + 2 * M1 + o);
            float4 p3 = *(const float4*)(P + 3 * M1 + o);
            s.x += p1.x + p2.x + p3.x; s.y += p1.y + p2.y + p3.y;
            s.z += p1.z + p2.z + p3.z; s.w += p1.w + p2.w + p3.w;
            float4 t;
            t.x = alpha * s.x; t.y = alpha * s.y;
            t.z = alpha * s.z; t.w = alpha * s.w;
            if (beta != 0.f) {
                const float4 ts = *(const float4*)(Tsub + o);
                t.x += beta * ts.x; t.y += beta * ts.y;
                t.z += beta * ts.z; t.w += beta * ts.w;
            }
            if (Tout) *(float4*)(Tout + o) = t;
            const int f0 = ac0 + 4 * j;
            ST[f0 + 0][arow] = t.x; ST[f0 + 1][arow] = t.y;
            ST[f0 + 2][arow] = t.z; ST[f0 + 3][arow] = t.w;
            if (Xin) {
                const float4 xv = *(const float4*)(Xin + o);
                ST2[f0 + 0][arow] = xv.x; ST2[f0 + 1][arow] = xv.y;
                ST2[f0 + 2][arow] = xv.z; ST2[f0 + 3][arow] = xv.w;
            }
        }
    }
    __syncthreads();

    // ---- phase B: transpose+split -> Th/Tl (optional)
    if (Th) {
        const int cc = tid >> 2;
        const int r0 = (tid & 3) * 16;
        float vals[16];
        *(float4*)&vals[0]  = *(const float4*)&ST[cc][r0];
        *(float4*)&vals[4]  = *(const float4*)&ST[cc][r0 + 4];
        *(float4*)&vals[8]  = *(const float4*)&ST[cc][r0 + 8];
        *(float4*)&vals[12] = *(const float4*)&ST[cc][r0 + 12];
        ushort_t hh[16], ll[16];
#pragma unroll
        for (int i = 0; i < 16; ++i) f32_split(vals[i], hh[i], ll[i]);
        unsigned wh[8], wl[8];
#pragma unroll
        for (int j = 0; j < 8; ++j) {
            wh[j] = (unsigned)hh[2 * j] | ((unsigned)hh[2 * j + 1] << 16);
            wl[j] = (unsigned)ll[2 * j] | ((unsigned)ll[2 * j + 1] << 16);
        }
        const size_t o = (size_t)cc * NN + rb + r0;
        *(uint4*)(Th + o)     = make_uint4(wh[0], wh[1], wh[2], wh[3]);
        *(uint4*)(Th + o + 8) = make_uint4(wh[4], wh[5], wh[6], wh[7]);
        *(uint4*)(Tl + o)     = make_uint4(wl[0], wl[1], wl[2], wl[3]);
        *(uint4*)(Tl + o + 8) = make_uint4(wl[4], wl[5], wl[6], wl[7]);
    }

    // ---- phase C: out accumulation, micro-tile 2 rows x 8 cols per thread
    {
        const int tx = tid & 7;
        const int ty = tid >> 3;
        const int col0 = tx * 8;
        const int row0 = ty * 2;
        float acc[2][8];
        if (Xin) {
            const float4 b0 = *(const float4*)(bias + col0);
            const float4 b1 = *(const float4*)(bias + col0 + 4);
#pragma unroll
            for (int r = 0; r < 2; ++r) {
                acc[r][0] = b0.x; acc[r][1] = b0.y; acc[r][2] = b0.z; acc[r][3] = b0.w;
                acc[r][4] = b1.x; acc[r][5] = b1.y; acc[r][6] = b1.z; acc[r][7] = b1.w;
            }
        } else {
#pragma unroll
            for (int r = 0; r < 2; ++r) {
                const size_t o = (size_t)(rb + row0 + r) * FF + col0;
                const float4 o0 = *(const float4*)(out + o);
                const float4 o1 = *(const float4*)(out + o + 4);
                acc[r][0] = o0.x; acc[r][1] = o0.y; acc[r][2] = o0.z; acc[r][3] = o0.w;
                acc[r][4] = o1.x; acc[r][5] = o1.y; acc[r][6] = o1.z; acc[r][7] = o1.w;
            }
        }
#pragma unroll
        for (int f = 0; f < FF; ++f) {
            const float2 lv = *(const float2*)&ST[f][row0];
            const float4 w0 = *(const float4*)&WK[f][col0];
            const float4 w1 = *(const float4*)&WK[f][col0 + 4];
            acc[0][0] += lv.x * w0.x; acc[0][1] += lv.x * w0.y;
            acc[0][2] += lv.x * w0.z; acc[0][3] += lv.x * w0.w;
            acc[0][4] += lv.x * w1.x; acc[0][5] += lv.x * w1.y;
            acc[0][6] += lv.x * w1.z; acc[0][7] += lv.x * w1.w;
            acc[1][0] += lv.y * w0.x; acc[1][1] += lv.y * w0.y;
            acc[1][2] += lv.y * w0.z; acc[1][3] += lv.y * w0.w;
            acc[1][4] += lv.y * w1.x; acc[1][5] += lv.y * w1.y;
            acc[1][6] += lv.y * w1.z; acc[1][7] += lv.y * w1.w;
        }
        if (Xin) {
#pragma unroll
            for (int f = 0; f < FF; ++f) {
                const float2 lv = *(const float2*)&ST2[f][row0];
                const float4 w0 = *(const float4*)&WX[f][col0];
                const float4 w1 = *(const float4*)&WX[f][col0 + 4];
                acc[0][0] += lv.x * w0.x; acc[0][1] += lv.x * w0.y;
                acc[0][2] += lv.x * w0.z; acc[0][3] += lv.x * w0.w;
                acc[0][4] += lv.x * w1.x; acc[0][5] += lv.x * w1.y;
                acc[0][6] += lv.x * w1.z; acc[0][7] += lv.x * w1.w;
                acc[1][0] += lv.y * w0.x; acc[1][1] += lv.y * w0.y;
                acc[1][2] += lv.y * w0.z; acc[1][3] += lv.y * w0.w;
                acc[1][4] += lv.y * w1.x; acc[1][5] += lv.y * w1.y;
                acc[1][6] += lv.y * w1.z; acc[1][7] += lv.y * w1.w;
            }
        }
#pragma unroll
        for (int r = 0; r < 2; ++r) {
            const size_t o = (size_t)(rb + row0 + r) * FF + col0;
            float4 v0, v1;
            v0.x = acc[r][0]; v0.y = acc[r][1]; v0.z = acc[r][2]; v0.w = acc[r][3];
            v1.x = acc[r][4]; v1.y = acc[r][5]; v1.z = acc[r][6]; v1.w = acc[r][7];
            *(float4*)(out + o) = v0;
            *(float4*)(out + o + 4) = v1;
        }
    }
}

extern "C" void kernel_launch(void* const* d_in, const int* in_sizes, int n_in,
                              void* d_out, int out_size, void* d_ws, size_t ws_size,
                              hipStream_t stream)
{
    const float* x    = (const float*)d_in[0];
    const float* L    = (const float*)d_in[1];
    const float* W    = (const float*)d_in[2];   // (4, 64, 64)
    const float* bias = (const float*)d_in[3];
    float* out = (float*)d_out;

    const size_t M1 = (size_t)NN * FF;           // 1M elems
    float* wsf = (float*)d_ws;
    float* T1 = wsf;                             // 4 MB
    float* P  = wsf + M1;                        // 4 partials, 16 MB
    ushort_t* Tht = (ushort_t*)(wsf + 5 * M1);   // 2 MB
    ushort_t* Tlt = Tht + M1;                    // 2 MB

    const dim3 gg(256 * SK), bg(256);            // gemm: 1024 blocks
    const dim3 gc(NN / 64),  bc(256);            // convT / post: 256 blocks

    // hop 1: T1 = L @ x ; out = bias + x@W0 + T1@W1
    convT<<<gc, bc, 0, stream>>>(x, Tht, Tlt);
    cheb_gemm_mfma<<<gg, bg, 0, stream>>>(L, Tht, Tlt, P);
    post_hop<<<gc, bc, 0, stream>>>(P, x, x, W + 0 * FF * FF, W + 1 * FF * FF,
                                    bias, T1, Tht, Tlt, out, 1.f, 0.f);
    // hop 2: T2 = 2*(L@T1) - x ; out += T2@W2   (T2 only lives as Th/Tl)
    cheb_gemm_mfma<<<gg, bg, 0, stream>>>(L, Tht, Tlt, P);
    post_hop<<<gc, bc, 0, stream>>>(P, x, nullptr, nullptr, W + 2 * FF * FF,
                                    bias, nullptr, Tht, Tlt, out, 2.f, -1.f);
    // hop 3: T3 = 2*(L@T2) - T1 ; out += T3@W3  (T3 never materialized)
    cheb_gemm_mfma<<<gg, bg, 0, stream>>>(L, Tht, Tlt, P);
    post_hop<<<gc, bc, 0, stream>>>(P, T1, nullptr, nullptr, W + 3 * FF * FF,
                                    bias, nullptr, nullptr, nullptr, out, 2.f, -1.f);
}